// Round 7
// baseline (124.880 us; speedup 1.0000x reference)
//
#include <hip/hip_runtime.h>
#include <hip/hip_bf16.h>
#include <hip/hip_fp8.h>

// ============================================================================
// ROUND 7 = A/B MEASUREMENT ROUND.
// Device code is byte-identical to the round-5 best (96.2 us).
// The ONLY change: k_agg is launched 3x (idempotent - reads phase-1 outputs,
// deterministically rewrites the same `out`). Readout: t_agg = (dur-96.2)/2.
// This splits "harness-fixed + phase1" from "agg" exactly, resolving whether
// the remaining time is ours at all (Model A) or mostly harness (Model B).
// ============================================================================

// Problem constants (fixed by reference): N=10000, D=128, E=640000.
#define NB    64       // sort blocks; each owns E/NB edges (dispatched first)
#define EPB   10000    // edges per sort block
#define NPAD  10240    // scan width: 256 threads * 40 nodes
#define NPT   40       // nodes per thread in scan
#define NGEMM 625      // gemm role blocks (10000/16)
#define LCAP  1024     // per-wave src-list capacity (max degree ~110 for this input)
#define SMEM_BYTES 40496  // sort: h 20480 + sorted 20000 + wsum 16 (gemm uses 8448)

typedef __bf16 bf16_8 __attribute__((ext_vector_type(8)));
typedef float f32_2 __attribute__((ext_vector_type(2)));
typedef float f32_4 __attribute__((ext_vector_type(4)));
typedef float f32_8 __attribute__((ext_vector_type(8)));

// ---------------------------------------------------------------------------
// gemm role: z = x @ W^T (bf16 MFMA); C-tile staged in LDS so the zb (bf16)
// and zb8 (fp8 e4m3) outputs are written with coalesced 16B/8B stores.
// (verified r1/r2/r4/r5 - unchanged)
// ---------------------------------------------------------------------------
__device__ __forceinline__ void gemm_role(unsigned char* smem, int bx,
    const float* __restrict__ x, const float* __restrict__ W,
    __hip_bfloat16* __restrict__ zb, unsigned char* __restrict__ zb8) {
  float* ctile = (float*)smem;  // [16][132] padded stride
  const int rowbase = bx * 16;
  const int wid = threadIdx.x >> 6;
  const int lane = threadIdx.x & 63;
  const int m16 = lane & 15;
  const int quad = lane >> 4;

  union { bf16_8 v; __hip_bfloat16 h8[8]; } ac[4];
  const float* arow = x + (size_t)(rowbase + m16) * 128 + quad * 8;
#pragma unroll
  for (int kk = 0; kk < 4; ++kk) {
    f32_8 af = *(const f32_8*)(arow + kk * 32);
#pragma unroll
    for (int j = 0; j < 8; ++j) ac[kk].h8[j] = __float2bfloat16(af[j]);
  }
#pragma unroll
  for (int ct = 0; ct < 2; ++ct) {
    int colbase = wid * 32 + ct * 16;
    const float* brow = W + (size_t)(colbase + m16) * 128 + quad * 8;
    f32_4 c = {0.f, 0.f, 0.f, 0.f};
#pragma unroll
    for (int kk = 0; kk < 4; ++kk) {
      f32_8 bf = *(const f32_8*)(brow + kk * 32);
      union { bf16_8 v; __hip_bfloat16 h8[8]; } bc;
#pragma unroll
      for (int j = 0; j < 8; ++j) bc.h8[j] = __float2bfloat16(bf[j]);
      c = __builtin_amdgcn_mfma_f32_16x16x32_bf16(ac[kk].v, bc.v, c, 0, 0, 0);
    }
#pragma unroll
    for (int r = 0; r < 4; ++r)
      ctile[(quad * 4 + r) * 132 + colbase + m16] = c[r];
  }
  __syncthreads();

  // coalesced write-out: thread t -> row t>>4, 8 features at (t&15)*8
  const int row = threadIdx.x >> 4;
  const int cs = (threadIdx.x & 15) * 8;
  const float* src = ctile + row * 132 + cs;
  f32_4 a0 = *(const f32_4*)(src);
  f32_4 a1 = *(const f32_4*)(src + 4);
  union { uint4 u; __hip_bfloat16 h[8]; } hb;
  union { uint2 u; unsigned char c[8]; } q8;
#pragma unroll
  for (int j = 0; j < 4; ++j) {
    hb.h[j] = __float2bfloat16(a0[j]);
    hb.h[4 + j] = __float2bfloat16(a1[j]);
    q8.c[j] = __hip_fp8_e4m3(a0[j]).__x;
    q8.c[4 + j] = __hip_fp8_e4m3(a1[j]).__x;
  }
  *(uint4*)(zb + (size_t)(rowbase + row) * 128 + cs) = hb.u;   // 16 B
  *(uint2*)(zb8 + (size_t)(rowbase + row) * 128 + cs) = q8.u;  // 8 B
}

// ---------------------------------------------------------------------------
// sort role: counting-sort 10000 edges by dst (LDS only), NB=64.
// Pass A/C manually paired (verified r2/r5).
// ---------------------------------------------------------------------------
__device__ __forceinline__ void sort_role(unsigned char* smem, int b,
    const int* __restrict__ ei, int E,
    unsigned short* __restrict__ bins, unsigned int* __restrict__ combo) {
  int* h = (int*)smem;                                       // 20480 B
  unsigned short* sorted = (unsigned short*)(smem + 20480);  // 20000 B
  int* wsum = (int*)(smem + 40480);                          // 16 B

  const int t = threadIdx.x;
  const int4* src4 = (const int4*)(ei) + b * (EPB / 4);
  const int4* dst4 = (const int4*)(ei + E) + b * (EPB / 4);

  for (int i = t; i < NPAD / 2; i += 256) h[i] = 0;
  __syncthreads();

  // Pass A: histogram (packed-pair u16 LDS atomics), paired loads.
#pragma unroll
  for (int k = 0; k < 4; ++k) {
    int i0 = t + k * 512;
    int4 d0 = dst4[i0];
    int4 d1 = dst4[i0 + 256];
    atomicAdd(&h[d0.x >> 1], 1 << ((d0.x & 1) * 16));
    atomicAdd(&h[d0.y >> 1], 1 << ((d0.y & 1) * 16));
    atomicAdd(&h[d0.z >> 1], 1 << ((d0.z & 1) * 16));
    atomicAdd(&h[d0.w >> 1], 1 << ((d0.w & 1) * 16));
    atomicAdd(&h[d1.x >> 1], 1 << ((d1.x & 1) * 16));
    atomicAdd(&h[d1.y >> 1], 1 << ((d1.y & 1) * 16));
    atomicAdd(&h[d1.z >> 1], 1 << ((d1.z & 1) * 16));
    atomicAdd(&h[d1.w >> 1], 1 << ((d1.w & 1) * 16));
  }
  {
    int4 d = dst4[2048 + t];
    atomicAdd(&h[d.x >> 1], 1 << ((d.x & 1) * 16));
    atomicAdd(&h[d.y >> 1], 1 << ((d.y & 1) * 16));
    atomicAdd(&h[d.z >> 1], 1 << ((d.z & 1) * 16));
    atomicAdd(&h[d.w >> 1], 1 << ((d.w & 1) * 16));
  }
  if (t < 196) {
    int4 d = dst4[2304 + t];
    atomicAdd(&h[d.x >> 1], 1 << ((d.x & 1) * 16));
    atomicAdd(&h[d.y >> 1], 1 << ((d.y & 1) * 16));
    atomicAdd(&h[d.z >> 1], 1 << ((d.z & 1) * 16));
    atomicAdd(&h[d.w >> 1], 1 << ((d.w & 1) * 16));
  }
  __syncthreads();

  // Pass B: block-wide exclusive scan; emit packed cursors + combo row.
  int raw[NPT];
  const int lo = t * NPT;  // even
  int sum = 0;
#pragma unroll
  for (int j = 0; j < NPT; j += 2) {
    int pair = h[(lo + j) >> 1];
    raw[j] = pair & 0xFFFF;
    raw[j + 1] = (pair >> 16) & 0xFFFF;
    sum += raw[j] + raw[j + 1];
  }
  int incl = sum;
#pragma unroll
  for (int off = 1; off < 64; off <<= 1) {
    int v = __shfl_up(incl, off);
    if ((t & 63) >= off) incl += v;
  }
  if ((t & 63) == 63) wsum[t >> 6] = incl;
  __syncthreads();
  int wb = 0;
  for (int w = 0; w < (t >> 6); ++w) wb += wsum[w];
  int run = wb + incl - sum;  // block-wide exclusive prefix for this range

  unsigned int cpack[NPT];
#pragma unroll
  for (int j = 0; j < NPT; j += 2) {
    int r0 = run; run += raw[j];
    int r1 = run; run += raw[j + 1];
    h[(lo + j) >> 1] = (r1 << 16) | r0;  // packed cursors for Pass C
    cpack[j]     = ((unsigned)raw[j] << 16) | (unsigned)r0;
    cpack[j + 1] = ((unsigned)raw[j + 1] << 16) | (unsigned)r1;
  }
  __syncthreads();

  // combo row write: fully coalesced (10 x uint4 per thread)
  unsigned int* crow = combo + (size_t)b * NPAD + lo;
#pragma unroll
  for (int j = 0; j < NPT; j += 4)
    *(uint4*)(crow + j) = make_uint4(cpack[j], cpack[j+1], cpack[j+2], cpack[j+3]);

  // Pass C: rank via packed-pair atomic rtn, scatter into LDS; paired loads.
#pragma unroll
  for (int k = 0; k < 4; ++k) {
    int i0 = t + k * 512;
    int4 s0 = src4[i0];
    int4 d0 = dst4[i0];
    int4 s1 = src4[i0 + 256];
    int4 d1 = dst4[i0 + 256];
    int ss[8] = {s0.x, s0.y, s0.z, s0.w, s1.x, s1.y, s1.z, s1.w};
    int dd[8] = {d0.x, d0.y, d0.z, d0.w, d1.x, d1.y, d1.z, d1.w};
#pragma unroll
    for (int u = 0; u < 8; ++u) {
      int nn = dd[u];
      int sh = (nn & 1) * 16;
      int pos = (atomicAdd(&h[nn >> 1], 1 << sh) >> sh) & 0xFFFF;
      sorted[pos] = (unsigned short)ss[u];
    }
  }
  {
    int4 s = src4[2048 + t];
    int4 d = dst4[2048 + t];
    int ss[4] = {s.x, s.y, s.z, s.w};
    int dd[4] = {d.x, d.y, d.z, d.w};
#pragma unroll
    for (int u = 0; u < 4; ++u) {
      int nn = dd[u];
      int sh = (nn & 1) * 16;
      int pos = (atomicAdd(&h[nn >> 1], 1 << sh) >> sh) & 0xFFFF;
      sorted[pos] = (unsigned short)ss[u];
    }
  }
  if (t < 196) {
    int4 s = src4[2304 + t];
    int4 d = dst4[2304 + t];
    int ss[4] = {s.x, s.y, s.z, s.w};
    int dd[4] = {d.x, d.y, d.z, d.w};
#pragma unroll
    for (int u = 0; u < 4; ++u) {
      int nn = dd[u];
      int sh = (nn & 1) * 16;
      int pos = (atomicAdd(&h[nn >> 1], 1 << sh) >> sh) & 0xFFFF;
      sorted[pos] = (unsigned short)ss[u];
    }
  }
  __syncthreads();

  // stream out coalesced (10000 ushort = 5000 uint)
  unsigned int* outb = (unsigned int*)(bins + (size_t)b * EPB);
  const unsigned int* s32 = (const unsigned int*)sorted;
  for (int i = t; i < EPB / 2; i += 256) outb[i] = s32[i];
}

__global__ void __launch_bounds__(256) k_phase1(
    const float* __restrict__ x, const int* __restrict__ ei,
    const float* __restrict__ W,
    __hip_bfloat16* __restrict__ zb, unsigned char* __restrict__ zb8,
    unsigned short* __restrict__ bins, unsigned int* __restrict__ combo, int E) {
  __shared__ __align__(16) unsigned char smem[SMEM_BYTES];
  // sort blocks FIRST: they are the phase-1 critical path
  if (blockIdx.x < NB) sort_role(smem, blockIdx.x, ei, E, bins, combo);
  else gemm_role(smem, blockIdx.x - NB, x, W, zb, zb8);
}

// ---------------------------------------------------------------------------
// k_agg: block = 4 nodes (one per wave), NB=64 -> exactly one segment/lane.
// (byte-identical to the r5 best: transpose + shfl-scan + per-wave list +
// VGPR-lean 8x uint2 gather; no min-waves bound)
// ---------------------------------------------------------------------------
__global__ void __launch_bounds__(256) k_agg(
    const unsigned int* __restrict__ combo, const unsigned short* __restrict__ bins,
    const unsigned char* __restrict__ zb8, const __hip_bfloat16* __restrict__ zb,
    const float* __restrict__ bias, float* __restrict__ out, int N) {
  __shared__ unsigned int trans[4][64];       // 1 KB
  __shared__ unsigned short list[4][LCAP];    // 8 KB

  const int t = threadIdx.x;
  const int wid = t >> 6;
  const int lane = t & 63;
  const int n0 = blockIdx.x * 4;

  if (t < 64) {
    uint4 cm = *(const uint4*)(combo + (size_t)t * NPAD + n0);
    trans[0][t] = cm.x; trans[1][t] = cm.y; trans[2][t] = cm.z; trans[3][t] = cm.w;
  }
  __syncthreads();   // the only block-wide barrier

  const int n = n0 + wid;
  unsigned int cc = trans[wid][lane];
  int c = (int)(cc >> 16);
  int o = (int)(cc & 0xFFFF);

  // wave-local exclusive scan of c -> slot p; m = wave total (true degree)
  int incl = c;
#pragma unroll
  for (int off = 1; off < 64; off <<= 1) {
    int v = __shfl_up(incl, off);
    if (lane >= off) incl += v;
  }
  const int m = __shfl(incl, 63);
  int p = incl - c;

  {
    const unsigned short* bk = bins + (size_t)lane * EPB + o;
    unsigned short* L = list[wid];
    unsigned short s0 = 0, s1 = 0, s2 = 0;
    if (c > 0) s0 = bk[0];             // independent guarded loads
    if (c > 1) s1 = bk[1];
    if (c > 2) s2 = bk[2];
    if (c > 0 && p < LCAP) L[p] = s0;
    if (c > 1 && p + 1 < LCAP) L[p + 1] = s1;
    if (c > 2 && p + 2 < LCAP) L[p + 2] = s2;
    for (int j = 3; j < c; ++j)        // tail: P(c>3 | lambda=1) ~ 2%
      if (p + j < LCAP) L[p + j] = bk[j];
  }
  // no barrier: list[wid] is produced and consumed by this wave only
  // (compiler orders the LDS write->read via lgkmcnt)

  const int g = lane >> 4;    // row-group (4 groups)
  const int sub = lane & 15;  // 8-B chunk of the 128-B fp8 row
  int mm = m < LCAP ? m : LCAP;
  const unsigned short* L = list[wid];
  const unsigned char* z8base = zb8 + sub * 8;

  float acc[8] = {0.f, 0.f, 0.f, 0.f, 0.f, 0.f, 0.f, 0.f};
  for (int e = 0; e < mm; e += 32) {
    // phase 1: issue up to 8 independent 8-B fp8 row loads
    uint2 v[8];
#pragma unroll
    for (int u = 0; u < 8; ++u) {
      int idx = e + u * 4 + g;
      v[u] = make_uint2(0u, 0u);
      if (idx < mm) {
        int s = L[idx];
        v[u] = *(const uint2*)(z8base + (size_t)s * 128);
      }
    }
    // phase 2: packed HW fp8->f32 decode + accumulate (0x00 decodes to 0.0)
#pragma unroll
    for (int u = 0; u < 8; ++u) {
      f32_2 p01 = __builtin_amdgcn_cvt_pk_f32_fp8((int)v[u].x, false);
      f32_2 p23 = __builtin_amdgcn_cvt_pk_f32_fp8((int)v[u].x, true);
      f32_2 p45 = __builtin_amdgcn_cvt_pk_f32_fp8((int)v[u].y, false);
      f32_2 p67 = __builtin_amdgcn_cvt_pk_f32_fp8((int)v[u].y, true);
      acc[0] += p01[0]; acc[1] += p01[1];
      acc[2] += p23[0]; acc[3] += p23[1];
      acc[4] += p45[0]; acc[5] += p45[1];
      acc[6] += p67[0]; acc[7] += p67[1];
    }
  }
#pragma unroll
  for (int k = 0; k < 8; ++k) {
    acc[k] += __shfl_xor(acc[k], 16);
    acc[k] += __shfl_xor(acc[k], 32);
  }

  if (g == 0 && n < N) {
    float inv = 1.f / (float)(m > 0 ? m : 1);
    bf16_8 zn = *(const bf16_8*)(zb + (size_t)n * 128 + sub * 8);
    f32_8 bv = *(const f32_8*)(bias + sub * 8);
    float r[8];
#pragma unroll
    for (int k = 0; k < 8; ++k) {
      float v2 = acc[k] * inv + (float)zn[k] + bv[k];
      r[k] = v2 > 0.f ? v2 : 0.f;
    }
    float* o2 = out + (size_t)n * 128 + sub * 8;
    *(float4*)(o2)     = make_float4(r[0], r[1], r[2], r[3]);
    *(float4*)(o2 + 4) = make_float4(r[4], r[5], r[6], r[7]);
  }
}

// ---------------------------------------------------------------------------
extern "C" void kernel_launch(void* const* d_in, const int* in_sizes, int n_in,
                              void* d_out, int out_size, void* d_ws, size_t ws_size,
                              hipStream_t stream) {
  const float* x = (const float*)d_in[0];
  const int* ei = (const int*)d_in[1];
  const float* W = (const float*)d_in[2];
  const float* b = (const float*)d_in[3];
  float* out = (float*)d_out;

  const int N = in_sizes[0] / 128;  // 10000
  const int E = in_sizes[1] / 2;    // 640000 (= NB * EPB)

  char* ws = (char*)d_ws;
  size_t off = 0;
  auto carve = [&](size_t bytes) {
    void* p = ws + off;
    off = (off + bytes + 255) & ~(size_t)255;
    return p;
  };
  __hip_bfloat16* zb = (__hip_bfloat16*)carve((size_t)N * 128 * 2);     // 2.56 MB
  unsigned char* zb8 = (unsigned char*)carve((size_t)N * 128);          // 1.28 MB
  unsigned short* bins = (unsigned short*)carve((size_t)NB * EPB * 2);  // 1.28 MB
  unsigned int* combo = (unsigned int*)carve((size_t)NB * NPAD * 4);    // 2.62 MB

  // 1) fused: per-block counting sort (64 blocks, first) || z = x@W^T
  k_phase1<<<NB + NGEMM, 256, 0, stream>>>(x, ei, W, zb, zb8, bins, combo, E);
  // 2) A/B MEASUREMENT: k_agg launched 3x (idempotent). t_agg = (dur-96.2)/2.
  k_agg<<<N / 4, 256, 0, stream>>>(combo, bins, zb8, zb, b, out, N);
  k_agg<<<N / 4, 256, 0, stream>>>(combo, bins, zb8, zb, b, out, N);
  k_agg<<<N / 4, 256, 0, stream>>>(combo, bins, zb8, zb, b, out, N);
}

// Round 8
// 121.507 us; speedup vs baseline: 1.0278x; 1.0278x over previous
//
#include <hip/hip_runtime.h>
#include <hip/hip_bf16.h>
#include <hip/hip_fp8.h>

// ============================================================================
// ROUND 8 = SECOND A/B MEASUREMENT ROUND.
// Device code byte-identical to the round-5 best (96.2 us).
// Round 7 established t_agg = (124.9-96.2)/2 = 14.3 us.
// This round: k_phase1 launched 3x (idempotent), k_agg 1x.
// Readout: t_p1 = (dur - 96.2)/2.  Completes the exact decomposition
// F (harness) + p1 + agg; next round acts on whichever is real.
// ============================================================================

// Problem constants (fixed by reference): N=10000, D=128, E=640000.
#define NB    64       // sort blocks; each owns E/NB edges (dispatched first)
#define EPB   10000    // edges per sort block
#define NPAD  10240    // scan width: 256 threads * 40 nodes
#define NPT   40       // nodes per thread in scan
#define NGEMM 625      // gemm role blocks (10000/16)
#define LCAP  1024     // per-wave src-list capacity (max degree ~110 for this input)
#define SMEM_BYTES 40496  // sort: h 20480 + sorted 20000 + wsum 16 (gemm uses 8448)

typedef __bf16 bf16_8 __attribute__((ext_vector_type(8)));
typedef float f32_2 __attribute__((ext_vector_type(2)));
typedef float f32_4 __attribute__((ext_vector_type(4)));
typedef float f32_8 __attribute__((ext_vector_type(8)));

// ---------------------------------------------------------------------------
// gemm role: z = x @ W^T (bf16 MFMA); C-tile staged in LDS so the zb (bf16)
// and zb8 (fp8 e4m3) outputs are written with coalesced 16B/8B stores.
// (verified r1/r2/r4/r5 - unchanged)
// ---------------------------------------------------------------------------
__device__ __forceinline__ void gemm_role(unsigned char* smem, int bx,
    const float* __restrict__ x, const float* __restrict__ W,
    __hip_bfloat16* __restrict__ zb, unsigned char* __restrict__ zb8) {
  float* ctile = (float*)smem;  // [16][132] padded stride
  const int rowbase = bx * 16;
  const int wid = threadIdx.x >> 6;
  const int lane = threadIdx.x & 63;
  const int m16 = lane & 15;
  const int quad = lane >> 4;

  union { bf16_8 v; __hip_bfloat16 h8[8]; } ac[4];
  const float* arow = x + (size_t)(rowbase + m16) * 128 + quad * 8;
#pragma unroll
  for (int kk = 0; kk < 4; ++kk) {
    f32_8 af = *(const f32_8*)(arow + kk * 32);
#pragma unroll
    for (int j = 0; j < 8; ++j) ac[kk].h8[j] = __float2bfloat16(af[j]);
  }
#pragma unroll
  for (int ct = 0; ct < 2; ++ct) {
    int colbase = wid * 32 + ct * 16;
    const float* brow = W + (size_t)(colbase + m16) * 128 + quad * 8;
    f32_4 c = {0.f, 0.f, 0.f, 0.f};
#pragma unroll
    for (int kk = 0; kk < 4; ++kk) {
      f32_8 bf = *(const f32_8*)(brow + kk * 32);
      union { bf16_8 v; __hip_bfloat16 h8[8]; } bc;
#pragma unroll
      for (int j = 0; j < 8; ++j) bc.h8[j] = __float2bfloat16(bf[j]);
      c = __builtin_amdgcn_mfma_f32_16x16x32_bf16(ac[kk].v, bc.v, c, 0, 0, 0);
    }
#pragma unroll
    for (int r = 0; r < 4; ++r)
      ctile[(quad * 4 + r) * 132 + colbase + m16] = c[r];
  }
  __syncthreads();

  // coalesced write-out: thread t -> row t>>4, 8 features at (t&15)*8
  const int row = threadIdx.x >> 4;
  const int cs = (threadIdx.x & 15) * 8;
  const float* src = ctile + row * 132 + cs;
  f32_4 a0 = *(const f32_4*)(src);
  f32_4 a1 = *(const f32_4*)(src + 4);
  union { uint4 u; __hip_bfloat16 h[8]; } hb;
  union { uint2 u; unsigned char c[8]; } q8;
#pragma unroll
  for (int j = 0; j < 4; ++j) {
    hb.h[j] = __float2bfloat16(a0[j]);
    hb.h[4 + j] = __float2bfloat16(a1[j]);
    q8.c[j] = __hip_fp8_e4m3(a0[j]).__x;
    q8.c[4 + j] = __hip_fp8_e4m3(a1[j]).__x;
  }
  *(uint4*)(zb + (size_t)(rowbase + row) * 128 + cs) = hb.u;   // 16 B
  *(uint2*)(zb8 + (size_t)(rowbase + row) * 128 + cs) = q8.u;  // 8 B
}

// ---------------------------------------------------------------------------
// sort role: counting-sort 10000 edges by dst (LDS only), NB=64.
// Pass A/C manually paired (verified r2/r5).
// ---------------------------------------------------------------------------
__device__ __forceinline__ void sort_role(unsigned char* smem, int b,
    const int* __restrict__ ei, int E,
    unsigned short* __restrict__ bins, unsigned int* __restrict__ combo) {
  int* h = (int*)smem;                                       // 20480 B
  unsigned short* sorted = (unsigned short*)(smem + 20480);  // 20000 B
  int* wsum = (int*)(smem + 40480);                          // 16 B

  const int t = threadIdx.x;
  const int4* src4 = (const int4*)(ei) + b * (EPB / 4);
  const int4* dst4 = (const int4*)(ei + E) + b * (EPB / 4);

  for (int i = t; i < NPAD / 2; i += 256) h[i] = 0;
  __syncthreads();

  // Pass A: histogram (packed-pair u16 LDS atomics), paired loads.
#pragma unroll
  for (int k = 0; k < 4; ++k) {
    int i0 = t + k * 512;
    int4 d0 = dst4[i0];
    int4 d1 = dst4[i0 + 256];
    atomicAdd(&h[d0.x >> 1], 1 << ((d0.x & 1) * 16));
    atomicAdd(&h[d0.y >> 1], 1 << ((d0.y & 1) * 16));
    atomicAdd(&h[d0.z >> 1], 1 << ((d0.z & 1) * 16));
    atomicAdd(&h[d0.w >> 1], 1 << ((d0.w & 1) * 16));
    atomicAdd(&h[d1.x >> 1], 1 << ((d1.x & 1) * 16));
    atomicAdd(&h[d1.y >> 1], 1 << ((d1.y & 1) * 16));
    atomicAdd(&h[d1.z >> 1], 1 << ((d1.z & 1) * 16));
    atomicAdd(&h[d1.w >> 1], 1 << ((d1.w & 1) * 16));
  }
  {
    int4 d = dst4[2048 + t];
    atomicAdd(&h[d.x >> 1], 1 << ((d.x & 1) * 16));
    atomicAdd(&h[d.y >> 1], 1 << ((d.y & 1) * 16));
    atomicAdd(&h[d.z >> 1], 1 << ((d.z & 1) * 16));
    atomicAdd(&h[d.w >> 1], 1 << ((d.w & 1) * 16));
  }
  if (t < 196) {
    int4 d = dst4[2304 + t];
    atomicAdd(&h[d.x >> 1], 1 << ((d.x & 1) * 16));
    atomicAdd(&h[d.y >> 1], 1 << ((d.y & 1) * 16));
    atomicAdd(&h[d.z >> 1], 1 << ((d.z & 1) * 16));
    atomicAdd(&h[d.w >> 1], 1 << ((d.w & 1) * 16));
  }
  __syncthreads();

  // Pass B: block-wide exclusive scan; emit packed cursors + combo row.
  int raw[NPT];
  const int lo = t * NPT;  // even
  int sum = 0;
#pragma unroll
  for (int j = 0; j < NPT; j += 2) {
    int pair = h[(lo + j) >> 1];
    raw[j] = pair & 0xFFFF;
    raw[j + 1] = (pair >> 16) & 0xFFFF;
    sum += raw[j] + raw[j + 1];
  }
  int incl = sum;
#pragma unroll
  for (int off = 1; off < 64; off <<= 1) {
    int v = __shfl_up(incl, off);
    if ((t & 63) >= off) incl += v;
  }
  if ((t & 63) == 63) wsum[t >> 6] = incl;
  __syncthreads();
  int wb = 0;
  for (int w = 0; w < (t >> 6); ++w) wb += wsum[w];
  int run = wb + incl - sum;  // block-wide exclusive prefix for this range

  unsigned int cpack[NPT];
#pragma unroll
  for (int j = 0; j < NPT; j += 2) {
    int r0 = run; run += raw[j];
    int r1 = run; run += raw[j + 1];
    h[(lo + j) >> 1] = (r1 << 16) | r0;  // packed cursors for Pass C
    cpack[j]     = ((unsigned)raw[j] << 16) | (unsigned)r0;
    cpack[j + 1] = ((unsigned)raw[j + 1] << 16) | (unsigned)r1;
  }
  __syncthreads();

  // combo row write: fully coalesced (10 x uint4 per thread)
  unsigned int* crow = combo + (size_t)b * NPAD + lo;
#pragma unroll
  for (int j = 0; j < NPT; j += 4)
    *(uint4*)(crow + j) = make_uint4(cpack[j], cpack[j+1], cpack[j+2], cpack[j+3]);

  // Pass C: rank via packed-pair atomic rtn, scatter into LDS; paired loads.
#pragma unroll
  for (int k = 0; k < 4; ++k) {
    int i0 = t + k * 512;
    int4 s0 = src4[i0];
    int4 d0 = dst4[i0];
    int4 s1 = src4[i0 + 256];
    int4 d1 = dst4[i0 + 256];
    int ss[8] = {s0.x, s0.y, s0.z, s0.w, s1.x, s1.y, s1.z, s1.w};
    int dd[8] = {d0.x, d0.y, d0.z, d0.w, d1.x, d1.y, d1.z, d1.w};
#pragma unroll
    for (int u = 0; u < 8; ++u) {
      int nn = dd[u];
      int sh = (nn & 1) * 16;
      int pos = (atomicAdd(&h[nn >> 1], 1 << sh) >> sh) & 0xFFFF;
      sorted[pos] = (unsigned short)ss[u];
    }
  }
  {
    int4 s = src4[2048 + t];
    int4 d = dst4[2048 + t];
    int ss[4] = {s.x, s.y, s.z, s.w};
    int dd[4] = {d.x, d.y, d.z, d.w};
#pragma unroll
    for (int u = 0; u < 4; ++u) {
      int nn = dd[u];
      int sh = (nn & 1) * 16;
      int pos = (atomicAdd(&h[nn >> 1], 1 << sh) >> sh) & 0xFFFF;
      sorted[pos] = (unsigned short)ss[u];
    }
  }
  if (t < 196) {
    int4 s = src4[2304 + t];
    int4 d = dst4[2304 + t];
    int ss[4] = {s.x, s.y, s.z, s.w};
    int dd[4] = {d.x, d.y, d.z, d.w};
#pragma unroll
    for (int u = 0; u < 4; ++u) {
      int nn = dd[u];
      int sh = (nn & 1) * 16;
      int pos = (atomicAdd(&h[nn >> 1], 1 << sh) >> sh) & 0xFFFF;
      sorted[pos] = (unsigned short)ss[u];
    }
  }
  __syncthreads();

  // stream out coalesced (10000 ushort = 5000 uint)
  unsigned int* outb = (unsigned int*)(bins + (size_t)b * EPB);
  const unsigned int* s32 = (const unsigned int*)sorted;
  for (int i = t; i < EPB / 2; i += 256) outb[i] = s32[i];
}

__global__ void __launch_bounds__(256) k_phase1(
    const float* __restrict__ x, const int* __restrict__ ei,
    const float* __restrict__ W,
    __hip_bfloat16* __restrict__ zb, unsigned char* __restrict__ zb8,
    unsigned short* __restrict__ bins, unsigned int* __restrict__ combo, int E) {
  __shared__ __align__(16) unsigned char smem[SMEM_BYTES];
  // sort blocks FIRST: they are the phase-1 critical path
  if (blockIdx.x < NB) sort_role(smem, blockIdx.x, ei, E, bins, combo);
  else gemm_role(smem, blockIdx.x - NB, x, W, zb, zb8);
}

// ---------------------------------------------------------------------------
// k_agg: block = 4 nodes (one per wave), NB=64 -> exactly one segment/lane.
// (byte-identical to the r5 best)
// ---------------------------------------------------------------------------
__global__ void __launch_bounds__(256) k_agg(
    const unsigned int* __restrict__ combo, const unsigned short* __restrict__ bins,
    const unsigned char* __restrict__ zb8, const __hip_bfloat16* __restrict__ zb,
    const float* __restrict__ bias, float* __restrict__ out, int N) {
  __shared__ unsigned int trans[4][64];       // 1 KB
  __shared__ unsigned short list[4][LCAP];    // 8 KB

  const int t = threadIdx.x;
  const int wid = t >> 6;
  const int lane = t & 63;
  const int n0 = blockIdx.x * 4;

  if (t < 64) {
    uint4 cm = *(const uint4*)(combo + (size_t)t * NPAD + n0);
    trans[0][t] = cm.x; trans[1][t] = cm.y; trans[2][t] = cm.z; trans[3][t] = cm.w;
  }
  __syncthreads();   // the only block-wide barrier

  const int n = n0 + wid;
  unsigned int cc = trans[wid][lane];
  int c = (int)(cc >> 16);
  int o = (int)(cc & 0xFFFF);

  // wave-local exclusive scan of c -> slot p; m = wave total (true degree)
  int incl = c;
#pragma unroll
  for (int off = 1; off < 64; off <<= 1) {
    int v = __shfl_up(incl, off);
    if (lane >= off) incl += v;
  }
  const int m = __shfl(incl, 63);
  int p = incl - c;

  {
    const unsigned short* bk = bins + (size_t)lane * EPB + o;
    unsigned short* L = list[wid];
    unsigned short s0 = 0, s1 = 0, s2 = 0;
    if (c > 0) s0 = bk[0];             // independent guarded loads
    if (c > 1) s1 = bk[1];
    if (c > 2) s2 = bk[2];
    if (c > 0 && p < LCAP) L[p] = s0;
    if (c > 1 && p + 1 < LCAP) L[p + 1] = s1;
    if (c > 2 && p + 2 < LCAP) L[p + 2] = s2;
    for (int j = 3; j < c; ++j)        // tail: P(c>3 | lambda=1) ~ 2%
      if (p + j < LCAP) L[p + j] = bk[j];
  }
  // no barrier: list[wid] is produced and consumed by this wave only
  // (compiler orders the LDS write->read via lgkmcnt)

  const int g = lane >> 4;    // row-group (4 groups)
  const int sub = lane & 15;  // 8-B chunk of the 128-B fp8 row
  int mm = m < LCAP ? m : LCAP;
  const unsigned short* L = list[wid];
  const unsigned char* z8base = zb8 + sub * 8;

  float acc[8] = {0.f, 0.f, 0.f, 0.f, 0.f, 0.f, 0.f, 0.f};
  for (int e = 0; e < mm; e += 32) {
    // phase 1: issue up to 8 independent 8-B fp8 row loads
    uint2 v[8];
#pragma unroll
    for (int u = 0; u < 8; ++u) {
      int idx = e + u * 4 + g;
      v[u] = make_uint2(0u, 0u);
      if (idx < mm) {
        int s = L[idx];
        v[u] = *(const uint2*)(z8base + (size_t)s * 128);
      }
    }
    // phase 2: packed HW fp8->f32 decode + accumulate (0x00 decodes to 0.0)
#pragma unroll
    for (int u = 0; u < 8; ++u) {
      f32_2 p01 = __builtin_amdgcn_cvt_pk_f32_fp8((int)v[u].x, false);
      f32_2 p23 = __builtin_amdgcn_cvt_pk_f32_fp8((int)v[u].x, true);
      f32_2 p45 = __builtin_amdgcn_cvt_pk_f32_fp8((int)v[u].y, false);
      f32_2 p67 = __builtin_amdgcn_cvt_pk_f32_fp8((int)v[u].y, true);
      acc[0] += p01[0]; acc[1] += p01[1];
      acc[2] += p23[0]; acc[3] += p23[1];
      acc[4] += p45[0]; acc[5] += p45[1];
      acc[6] += p67[0]; acc[7] += p67[1];
    }
  }
#pragma unroll
  for (int k = 0; k < 8; ++k) {
    acc[k] += __shfl_xor(acc[k], 16);
    acc[k] += __shfl_xor(acc[k], 32);
  }

  if (g == 0 && n < N) {
    float inv = 1.f / (float)(m > 0 ? m : 1);
    bf16_8 zn = *(const bf16_8*)(zb + (size_t)n * 128 + sub * 8);
    f32_8 bv = *(const f32_8*)(bias + sub * 8);
    float r[8];
#pragma unroll
    for (int k = 0; k < 8; ++k) {
      float v2 = acc[k] * inv + (float)zn[k] + bv[k];
      r[k] = v2 > 0.f ? v2 : 0.f;
    }
    float* o2 = out + (size_t)n * 128 + sub * 8;
    *(float4*)(o2)     = make_float4(r[0], r[1], r[2], r[3]);
    *(float4*)(o2 + 4) = make_float4(r[4], r[5], r[6], r[7]);
  }
}

// ---------------------------------------------------------------------------
extern "C" void kernel_launch(void* const* d_in, const int* in_sizes, int n_in,
                              void* d_out, int out_size, void* d_ws, size_t ws_size,
                              hipStream_t stream) {
  const float* x = (const float*)d_in[0];
  const int* ei = (const int*)d_in[1];
  const float* W = (const float*)d_in[2];
  const float* b = (const float*)d_in[3];
  float* out = (float*)d_out;

  const int N = in_sizes[0] / 128;  // 10000
  const int E = in_sizes[1] / 2;    // 640000 (= NB * EPB)

  char* ws = (char*)d_ws;
  size_t off = 0;
  auto carve = [&](size_t bytes) {
    void* p = ws + off;
    off = (off + bytes + 255) & ~(size_t)255;
    return p;
  };
  __hip_bfloat16* zb = (__hip_bfloat16*)carve((size_t)N * 128 * 2);     // 2.56 MB
  unsigned char* zb8 = (unsigned char*)carve((size_t)N * 128);          // 1.28 MB
  unsigned short* bins = (unsigned short*)carve((size_t)NB * EPB * 2);  // 1.28 MB
  unsigned int* combo = (unsigned int*)carve((size_t)NB * NPAD * 4);    // 2.62 MB

  // A/B MEASUREMENT: k_phase1 launched 3x (idempotent). t_p1 = (dur-96.2)/2.
  k_phase1<<<NB + NGEMM, 256, 0, stream>>>(x, ei, W, zb, zb8, bins, combo, E);
  k_phase1<<<NB + NGEMM, 256, 0, stream>>>(x, ei, W, zb, zb8, bins, combo, E);
  k_phase1<<<NB + NGEMM, 256, 0, stream>>>(x, ei, W, zb, zb8, bins, combo, E);
  // 2) segment-sum + fp8 gather + /deg + z[n] + bias + relu
  k_agg<<<N / 4, 256, 0, stream>>>(combo, bins, zb8, zb, b, out, N);
}

// Round 9
// 94.143 us; speedup vs baseline: 1.3265x; 1.2907x over previous
//
#include <hip/hip_runtime.h>
#include <hip/hip_bf16.h>
#include <hip/hip_fp8.h>

// Problem constants (fixed by reference): N=10000, D=128, E=640000.
// Round-8 decomposition of the 96.2-us best: harness ~69 us fixed,
// k_phase1 12.7 us (sort-atomic-bound), k_agg 14.3 us.
// This round: NB 64 -> 128 halves the per-block LDS-atomic critical path.
#define NB    128      // sort blocks; each owns E/NB edges (dispatched first)
#define EPB   5000     // edges per sort block
#define NPAD  10240    // scan width: 256 threads * 40 nodes
#define NPT   40       // nodes per thread in scan
#define NGEMM 625      // gemm role blocks (10000/16)
#define LCAP  1024     // per-wave src-list capacity (max degree ~110 for this input)
#define SMEM_BYTES 30496  // sort: h 20480 + sorted 10000 + wsum 16 (gemm uses 8448)

typedef __bf16 bf16_8 __attribute__((ext_vector_type(8)));
typedef float f32_2 __attribute__((ext_vector_type(2)));
typedef float f32_4 __attribute__((ext_vector_type(4)));
typedef float f32_8 __attribute__((ext_vector_type(8)));

// ---------------------------------------------------------------------------
// gemm role: z = x @ W^T (bf16 MFMA); C-tile staged in LDS so the zb (bf16)
// and zb8 (fp8 e4m3) outputs are written with coalesced 16B/8B stores.
// (verified r1/r2/r4/r5 - unchanged)
// ---------------------------------------------------------------------------
__device__ __forceinline__ void gemm_role(unsigned char* smem, int bx,
    const float* __restrict__ x, const float* __restrict__ W,
    __hip_bfloat16* __restrict__ zb, unsigned char* __restrict__ zb8) {
  float* ctile = (float*)smem;  // [16][132] padded stride
  const int rowbase = bx * 16;
  const int wid = threadIdx.x >> 6;
  const int lane = threadIdx.x & 63;
  const int m16 = lane & 15;
  const int quad = lane >> 4;

  union { bf16_8 v; __hip_bfloat16 h8[8]; } ac[4];
  const float* arow = x + (size_t)(rowbase + m16) * 128 + quad * 8;
#pragma unroll
  for (int kk = 0; kk < 4; ++kk) {
    f32_8 af = *(const f32_8*)(arow + kk * 32);
#pragma unroll
    for (int j = 0; j < 8; ++j) ac[kk].h8[j] = __float2bfloat16(af[j]);
  }
#pragma unroll
  for (int ct = 0; ct < 2; ++ct) {
    int colbase = wid * 32 + ct * 16;
    const float* brow = W + (size_t)(colbase + m16) * 128 + quad * 8;
    f32_4 c = {0.f, 0.f, 0.f, 0.f};
#pragma unroll
    for (int kk = 0; kk < 4; ++kk) {
      f32_8 bf = *(const f32_8*)(brow + kk * 32);
      union { bf16_8 v; __hip_bfloat16 h8[8]; } bc;
#pragma unroll
      for (int j = 0; j < 8; ++j) bc.h8[j] = __float2bfloat16(bf[j]);
      c = __builtin_amdgcn_mfma_f32_16x16x32_bf16(ac[kk].v, bc.v, c, 0, 0, 0);
    }
#pragma unroll
    for (int r = 0; r < 4; ++r)
      ctile[(quad * 4 + r) * 132 + colbase + m16] = c[r];
  }
  __syncthreads();

  // coalesced write-out: thread t -> row t>>4, 8 features at (t&15)*8
  const int row = threadIdx.x >> 4;
  const int cs = (threadIdx.x & 15) * 8;
  const float* src = ctile + row * 132 + cs;
  f32_4 a0 = *(const f32_4*)(src);
  f32_4 a1 = *(const f32_4*)(src + 4);
  union { uint4 u; __hip_bfloat16 h[8]; } hb;
  union { uint2 u; unsigned char c[8]; } q8;
#pragma unroll
  for (int j = 0; j < 4; ++j) {
    hb.h[j] = __float2bfloat16(a0[j]);
    hb.h[4 + j] = __float2bfloat16(a1[j]);
    q8.c[j] = __hip_fp8_e4m3(a0[j]).__x;
    q8.c[4 + j] = __hip_fp8_e4m3(a1[j]).__x;
  }
  *(uint4*)(zb + (size_t)(rowbase + row) * 128 + cs) = hb.u;   // 16 B
  *(uint2*)(zb8 + (size_t)(rowbase + row) * 128 + cs) = q8.u;  // 8 B
}

// ---------------------------------------------------------------------------
// sort role: counting-sort EPB=5000 edges by dst (LDS only), NB=128.
// HALF the per-block LDS-atomic work of the NB=64 version (the measured
// phase-1 pole). Pass A/C paired loads (verified r2/r5).
// Coverage of EPB/4=1250 int4: pairs {t,t+256},{t+512,t+768} -> [0,1024);
// then 1024+t (t<226) -> [1024,1250).
// ---------------------------------------------------------------------------
__device__ __forceinline__ void sort_role(unsigned char* smem, int b,
    const int* __restrict__ ei, int E,
    unsigned short* __restrict__ bins, unsigned int* __restrict__ combo) {
  int* h = (int*)smem;                                       // 20480 B
  unsigned short* sorted = (unsigned short*)(smem + 20480);  // 10000 B
  int* wsum = (int*)(smem + 30480);                          // 16 B

  const int t = threadIdx.x;
  const int4* src4 = (const int4*)(ei) + b * (EPB / 4);
  const int4* dst4 = (const int4*)(ei + E) + b * (EPB / 4);

  for (int i = t; i < NPAD / 2; i += 256) h[i] = 0;
  __syncthreads();

  // Pass A: histogram (packed-pair u16 LDS atomics), paired loads.
#pragma unroll
  for (int k = 0; k < 2; ++k) {
    int i0 = t + k * 512;
    int4 d0 = dst4[i0];
    int4 d1 = dst4[i0 + 256];
    atomicAdd(&h[d0.x >> 1], 1 << ((d0.x & 1) * 16));
    atomicAdd(&h[d0.y >> 1], 1 << ((d0.y & 1) * 16));
    atomicAdd(&h[d0.z >> 1], 1 << ((d0.z & 1) * 16));
    atomicAdd(&h[d0.w >> 1], 1 << ((d0.w & 1) * 16));
    atomicAdd(&h[d1.x >> 1], 1 << ((d1.x & 1) * 16));
    atomicAdd(&h[d1.y >> 1], 1 << ((d1.y & 1) * 16));
    atomicAdd(&h[d1.z >> 1], 1 << ((d1.z & 1) * 16));
    atomicAdd(&h[d1.w >> 1], 1 << ((d1.w & 1) * 16));
  }
  if (t < 226) {
    int4 d = dst4[1024 + t];
    atomicAdd(&h[d.x >> 1], 1 << ((d.x & 1) * 16));
    atomicAdd(&h[d.y >> 1], 1 << ((d.y & 1) * 16));
    atomicAdd(&h[d.z >> 1], 1 << ((d.z & 1) * 16));
    atomicAdd(&h[d.w >> 1], 1 << ((d.w & 1) * 16));
  }
  __syncthreads();

  // Pass B: block-wide exclusive scan; emit packed cursors + combo row.
  int raw[NPT];
  const int lo = t * NPT;  // even
  int sum = 0;
#pragma unroll
  for (int j = 0; j < NPT; j += 2) {
    int pair = h[(lo + j) >> 1];
    raw[j] = pair & 0xFFFF;
    raw[j + 1] = (pair >> 16) & 0xFFFF;
    sum += raw[j] + raw[j + 1];
  }
  int incl = sum;
#pragma unroll
  for (int off = 1; off < 64; off <<= 1) {
    int v = __shfl_up(incl, off);
    if ((t & 63) >= off) incl += v;
  }
  if ((t & 63) == 63) wsum[t >> 6] = incl;
  __syncthreads();
  int wb = 0;
  for (int w = 0; w < (t >> 6); ++w) wb += wsum[w];
  int run = wb + incl - sum;  // block-wide exclusive prefix for this range

  unsigned int cpack[NPT];
#pragma unroll
  for (int j = 0; j < NPT; j += 2) {
    int r0 = run; run += raw[j];
    int r1 = run; run += raw[j + 1];
    h[(lo + j) >> 1] = (r1 << 16) | r0;  // packed cursors for Pass C
    cpack[j]     = ((unsigned)raw[j] << 16) | (unsigned)r0;
    cpack[j + 1] = ((unsigned)raw[j + 1] << 16) | (unsigned)r1;
  }
  __syncthreads();

  // combo row write: fully coalesced (10 x uint4 per thread)
  unsigned int* crow = combo + (size_t)b * NPAD + lo;
#pragma unroll
  for (int j = 0; j < NPT; j += 4)
    *(uint4*)(crow + j) = make_uint4(cpack[j], cpack[j+1], cpack[j+2], cpack[j+3]);

  // Pass C: rank via packed-pair atomic rtn, scatter into LDS; paired loads.
#pragma unroll
  for (int k = 0; k < 2; ++k) {
    int i0 = t + k * 512;
    int4 s0 = src4[i0];
    int4 d0 = dst4[i0];
    int4 s1 = src4[i0 + 256];
    int4 d1 = dst4[i0 + 256];
    int ss[8] = {s0.x, s0.y, s0.z, s0.w, s1.x, s1.y, s1.z, s1.w};
    int dd[8] = {d0.x, d0.y, d0.z, d0.w, d1.x, d1.y, d1.z, d1.w};
#pragma unroll
    for (int u = 0; u < 8; ++u) {
      int nn = dd[u];
      int sh = (nn & 1) * 16;
      int pos = (atomicAdd(&h[nn >> 1], 1 << sh) >> sh) & 0xFFFF;
      sorted[pos] = (unsigned short)ss[u];
    }
  }
  if (t < 226) {
    int4 s = src4[1024 + t];
    int4 d = dst4[1024 + t];
    int ss[4] = {s.x, s.y, s.z, s.w};
    int dd[4] = {d.x, d.y, d.z, d.w};
#pragma unroll
    for (int u = 0; u < 4; ++u) {
      int nn = dd[u];
      int sh = (nn & 1) * 16;
      int pos = (atomicAdd(&h[nn >> 1], 1 << sh) >> sh) & 0xFFFF;
      sorted[pos] = (unsigned short)ss[u];
    }
  }
  __syncthreads();

  // stream out coalesced (5000 ushort = 2500 uint)
  unsigned int* outb = (unsigned int*)(bins + (size_t)b * EPB);
  const unsigned int* s32 = (const unsigned int*)sorted;
  for (int i = t; i < EPB / 2; i += 256) outb[i] = s32[i];
}

__global__ void __launch_bounds__(256) k_phase1(
    const float* __restrict__ x, const int* __restrict__ ei,
    const float* __restrict__ W,
    __hip_bfloat16* __restrict__ zb, unsigned char* __restrict__ zb8,
    unsigned short* __restrict__ bins, unsigned int* __restrict__ combo, int E) {
  __shared__ __align__(16) unsigned char smem[SMEM_BYTES];
  // sort blocks FIRST: they are the phase-1 critical path
  if (blockIdx.x < NB) sort_role(smem, blockIdx.x, ei, E, bins, combo);
  else gemm_role(smem, blockIdx.x - NB, x, W, zb, zb8);
}

// ---------------------------------------------------------------------------
// k_agg: block = 4 nodes (one per wave), NB=128 -> TWO segments per lane
// (lane l owns sort blocks l and l+64). Same verified structure as r5:
// coalesced transpose (now 128 threads x uint4), wave-local __shfl_up scan,
// per-wave list with only ONE block barrier, VGPR-lean 8x uint2 gather.
// NO min-waves launch bound (r2 lesson).
// ---------------------------------------------------------------------------
__global__ void __launch_bounds__(256) k_agg(
    const unsigned int* __restrict__ combo, const unsigned short* __restrict__ bins,
    const unsigned char* __restrict__ zb8, const __hip_bfloat16* __restrict__ zb,
    const float* __restrict__ bias, float* __restrict__ out, int N) {
  __shared__ unsigned int trans[4][128];      // 2 KB
  __shared__ unsigned short list[4][LCAP];    // 8 KB

  const int t = threadIdx.x;
  const int wid = t >> 6;
  const int lane = t & 63;
  const int n0 = blockIdx.x * 4;

  if (t < 128) {
    uint4 cm = *(const uint4*)(combo + (size_t)t * NPAD + n0);
    trans[0][t] = cm.x; trans[1][t] = cm.y; trans[2][t] = cm.z; trans[3][t] = cm.w;
  }
  __syncthreads();   // the only block-wide barrier

  const int n = n0 + wid;
  unsigned int cc0 = trans[wid][lane];
  unsigned int cc1 = trans[wid][lane + 64];
  const int c0 = (int)(cc0 >> 16), o0 = (int)(cc0 & 0xFFFF);
  const int c1 = (int)(cc1 >> 16), o1 = (int)(cc1 & 0xFFFF);
  const int c = c0 + c1;

  // wave-local exclusive scan of c -> slot p; m = wave total (true degree)
  int incl = c;
#pragma unroll
  for (int off = 1; off < 64; off <<= 1) {
    int v = __shfl_up(incl, off);
    if (lane >= off) incl += v;
  }
  const int m = __shfl(incl, 63);
  const int p = incl - c;

  {
    unsigned short* L = list[wid];
    // segment 0 (sort block = lane), lambda=0.5
    const unsigned short* bk0 = bins + (size_t)lane * EPB + o0;
    // segment 1 (sort block = lane+64)
    const unsigned short* bk1 = bins + (size_t)(lane + 64) * EPB + o1;
    unsigned short a0 = 0, a1 = 0, b0 = 0, b1 = 0;
    if (c0 > 0) a0 = bk0[0];           // independent guarded loads (MLP)
    if (c0 > 1) a1 = bk0[1];
    if (c1 > 0) b0 = bk1[0];
    if (c1 > 1) b1 = bk1[1];
    if (c0 > 0 && p < LCAP) L[p] = a0;
    if (c0 > 1 && p + 1 < LCAP) L[p + 1] = a1;
    for (int j = 2; j < c0; ++j)       // tail: P(c0>2 | lambda=0.5) ~ 1.4%
      if (p + j < LCAP) L[p + j] = bk0[j];
    const int q = p + c0;
    if (c1 > 0 && q < LCAP) L[q] = b0;
    if (c1 > 1 && q + 1 < LCAP) L[q + 1] = b1;
    for (int j = 2; j < c1; ++j)
      if (q + j < LCAP) L[q + j] = bk1[j];
  }
  // no barrier: list[wid] is produced and consumed by this wave only
  // (compiler orders the LDS write->read via lgkmcnt)

  const int g = lane >> 4;    // row-group (4 groups)
  const int sub = lane & 15;  // 8-B chunk of the 128-B fp8 row
  int mm = m < LCAP ? m : LCAP;
  const unsigned short* L = list[wid];
  const unsigned char* z8base = zb8 + sub * 8;

  float acc[8] = {0.f, 0.f, 0.f, 0.f, 0.f, 0.f, 0.f, 0.f};
  for (int e = 0; e < mm; e += 32) {
    // phase 1: issue up to 8 independent 8-B fp8 row loads
    uint2 v[8];
#pragma unroll
    for (int u = 0; u < 8; ++u) {
      int idx = e + u * 4 + g;
      v[u] = make_uint2(0u, 0u);
      if (idx < mm) {
        int s = L[idx];
        v[u] = *(const uint2*)(z8base + (size_t)s * 128);
      }
    }
    // phase 2: packed HW fp8->f32 decode + accumulate (0x00 decodes to 0.0)
#pragma unroll
    for (int u = 0; u < 8; ++u) {
      f32_2 p01 = __builtin_amdgcn_cvt_pk_f32_fp8((int)v[u].x, false);
      f32_2 p23 = __builtin_amdgcn_cvt_pk_f32_fp8((int)v[u].x, true);
      f32_2 p45 = __builtin_amdgcn_cvt_pk_f32_fp8((int)v[u].y, false);
      f32_2 p67 = __builtin_amdgcn_cvt_pk_f32_fp8((int)v[u].y, true);
      acc[0] += p01[0]; acc[1] += p01[1];
      acc[2] += p23[0]; acc[3] += p23[1];
      acc[4] += p45[0]; acc[5] += p45[1];
      acc[6] += p67[0]; acc[7] += p67[1];
    }
  }
#pragma unroll
  for (int k = 0; k < 8; ++k) {
    acc[k] += __shfl_xor(acc[k], 16);
    acc[k] += __shfl_xor(acc[k], 32);
  }

  if (g == 0 && n < N) {
    float inv = 1.f / (float)(m > 0 ? m : 1);
    bf16_8 zn = *(const bf16_8*)(zb + (size_t)n * 128 + sub * 8);
    f32_8 bv = *(const f32_8*)(bias + sub * 8);
    float r[8];
#pragma unroll
    for (int k = 0; k < 8; ++k) {
      float v2 = acc[k] * inv + (float)zn[k] + bv[k];
      r[k] = v2 > 0.f ? v2 : 0.f;
    }
    float* o2 = out + (size_t)n * 128 + sub * 8;
    *(float4*)(o2)     = make_float4(r[0], r[1], r[2], r[3]);
    *(float4*)(o2 + 4) = make_float4(r[4], r[5], r[6], r[7]);
  }
}

// ---------------------------------------------------------------------------
extern "C" void kernel_launch(void* const* d_in, const int* in_sizes, int n_in,
                              void* d_out, int out_size, void* d_ws, size_t ws_size,
                              hipStream_t stream) {
  const float* x = (const float*)d_in[0];
  const int* ei = (const int*)d_in[1];
  const float* W = (const float*)d_in[2];
  const float* b = (const float*)d_in[3];
  float* out = (float*)d_out;

  const int N = in_sizes[0] / 128;  // 10000
  const int E = in_sizes[1] / 2;    // 640000 (= NB * EPB)

  char* ws = (char*)d_ws;
  size_t off = 0;
  auto carve = [&](size_t bytes) {
    void* p = ws + off;
    off = (off + bytes + 255) & ~(size_t)255;
    return p;
  };
  __hip_bfloat16* zb = (__hip_bfloat16*)carve((size_t)N * 128 * 2);     // 2.56 MB
  unsigned char* zb8 = (unsigned char*)carve((size_t)N * 128);          // 1.28 MB
  unsigned short* bins = (unsigned short*)carve((size_t)NB * EPB * 2);  // 1.28 MB
  unsigned int* combo = (unsigned int*)carve((size_t)NB * NPAD * 4);    // 5.24 MB

  // 1) fused: per-block counting sort (128 blocks, first) || z = x@W^T
  k_phase1<<<NB + NGEMM, 256, 0, stream>>>(x, ei, W, zb, zb8, bins, combo, E);
  // 2) segment-sum + fp8 gather + /deg + z[n] + bias + relu
  k_agg<<<N / 4, 256, 0, stream>>>(combo, bins, zb8, zb, b, out, N);
}